// Round 2
// 537.808 us; speedup vs baseline: 1.0931x; 1.0931x over previous
//
#include <hip/hip_runtime.h>

// out[b, f, s] = x[b, 0, s] * w[f, s] + bias[f, s]
// B=128, F=256, S=4096  -> out: 134,217,728 fp32 (536.9 MB)
//
// Loop inversion: one thread owns (f, s4), holds w4/b4 in registers, loops
// over a 32-batch chunk. Read traffic drops from ~1.6 GB (w/bias re-streamed
// per batch, thrashing the 4 MB per-XCD L2) to:
//   - w/bias: 8 MB x 4 chunks = 32 MB from HBM
//   - x: 512 KB resident per chunk in every XCD L2 (demand reads are L2 hits)
// Output stores are nontemporal so the 537 MB write stream doesn't evict the
// resident inputs. Kernel becomes pure write-BW bound (~537 MB / 6.2 TB/s).
//
// NOTE: __builtin_nontemporal_store requires a NATIVE vector type, not HIP's
// float4 class — use clang ext_vector_type(4).

#define BATCH  128
#define NFILT  256
#define SEQ    4096
#define SEQ4   (SEQ / 4)            // 1024 float4 per row
#define BCHUNK 32                   // batches per thread
#define NBCHUNK (BATCH / BCHUNK)    // 4 chunks
#define TILES  (NFILT * SEQ4 / 256) // 1024 blocks per chunk

typedef float f32x4 __attribute__((ext_vector_type(4)));

__global__ __launch_bounds__(256) void dfe_kernel(
    const float* __restrict__ x,      // [BATCH, SEQ]
    const float* __restrict__ w,      // [NFILT, SEQ]
    const float* __restrict__ bias,   // [NFILT, SEQ]
    float* __restrict__ out)          // [BATCH, NFILT, SEQ]
{
    unsigned bid   = blockIdx.x;
    unsigned tile  = bid & (TILES - 1);   // low 10 bits: which (f,s4) tile
    unsigned chunk = bid >> 10;           // high bits: which batch chunk

    unsigned tid = tile * 256u + threadIdx.x;   // 0 .. NFILT*SEQ4-1
    unsigned s4  = tid & (SEQ4 - 1);
    unsigned f   = tid >> 10;

    // Per-thread invariant operands: held in registers for the whole b-loop.
    const f32x4 w4 = ((const f32x4*)w)[(size_t)f * SEQ4 + s4];
    const f32x4 b4 = ((const f32x4*)bias)[(size_t)f * SEQ4 + s4];

    const f32x4* xp = (const f32x4*)x + (size_t)chunk * BCHUNK * SEQ4 + s4;
    f32x4* op = (f32x4*)out
              + ((size_t)chunk * BCHUNK * NFILT + f) * SEQ4 + s4;

    #pragma unroll 4
    for (int b = 0; b < BCHUNK; ++b) {
        f32x4 x4 = xp[(size_t)b * SEQ4];            // L2 hit after first touch
        f32x4 o;
        o.x = fmaf(x4.x, w4.x, b4.x);
        o.y = fmaf(x4.y, w4.y, b4.y);
        o.z = fmaf(x4.z, w4.z, b4.z);
        o.w = fmaf(x4.w, w4.w, b4.w);
        // streaming store: don't pollute L2 with the 537 MB output
        __builtin_nontemporal_store(o, op + (size_t)b * (NFILT * SEQ4));
    }
}

extern "C" void kernel_launch(void* const* d_in, const int* in_sizes, int n_in,
                              void* d_out, int out_size, void* d_ws, size_t ws_size,
                              hipStream_t stream) {
    const float* x    = (const float*)d_in[0];   // (128, 1, 4096) fp32
    const float* w    = (const float*)d_in[1];   // (256, 4096)    fp32
    const float* bias = (const float*)d_in[2];   // (256, 4096)    fp32
    float* out = (float*)d_out;                  // (128, 256, 4096) fp32

    const int block = 256;
    const unsigned grid = TILES * NBCHUNK;       // 4096 blocks
    dfe_kernel<<<dim3(grid), dim3(block), 0, stream>>>(x, w, bias, out);
}